// Round 2
// baseline (1644.164 us; speedup 1.0000x reference)
//
#include <hip/hip_runtime.h>
#include <math.h>

#define DD 64
#define HIDN 32
#define NH 3
#define WPB 4   // waves per 256-thread block, one segment per wave

// ---------------------------------------------------------------------------
// Kernel 1: segment offsets. seg_start[g] = first i with owner[i] >= g
// (lower_bound). owner is sorted; gap-fill handles empty segments.
// ---------------------------------------------------------------------------
__global__ void seg_offsets_k(const int* __restrict__ owner, int N, int G,
                              int* __restrict__ seg_start) {
    int i = blockIdx.x * blockDim.x + threadIdx.x;
    if (i >= N) return;
    int cur  = owner[i];
    int prev = (i == 0) ? -1 : owner[i - 1];
    for (int g = prev + 1; g <= cur; ++g) seg_start[g] = i;
    if (i == N - 1) {
        for (int g = cur + 1; g <= G; ++g) seg_start[g] = N;
    }
}

__device__ __forceinline__ float lane_bcast(float v, int l) {
    // readlane: SGPR broadcast, cheap, exec-independent. l is wave-uniform.
    return __int_as_float(__builtin_amdgcn_readlane(__float_as_int(v), l));
}

// ---------------------------------------------------------------------------
// Per-atom MLP: scores = silu(x @ w1 + b1) @ w2 + b2   (fp32 throughout)
// hid[32] accumulators = 32 independent FMA chains (issue-bound).
// Double-buffered 4x float4 prefetch: one vmcnt wait per 16-row chunk
// instead of one per float4. w1/b1/w2/b2 reads are lane-uniform -> s_load.
// ---------------------------------------------------------------------------
__device__ __forceinline__ void mlp_scores(const float* __restrict__ fr,
                                           const float* __restrict__ w1,
                                           const float* __restrict__ b1,
                                           const float* __restrict__ w2,
                                           const float* __restrict__ b2,
                                           float& s0, float& s1, float& s2) {
    const float4* fr4 = (const float4*)fr;
    float hid[HIDN];
#pragma unroll
    for (int j = 0; j < HIDN; ++j) hid[j] = b1[j];

    float4 cur[4], nxt[4];
#pragma unroll
    for (int t = 0; t < 4; ++t) cur[t] = fr4[t];
#pragma unroll
    for (int c = 0; c < 4; ++c) {
        if (c < 3) {
#pragma unroll
            for (int t = 0; t < 4; ++t) nxt[t] = fr4[(c + 1) * 4 + t];
        }
#pragma unroll
        for (int t = 0; t < 4; ++t) {
            const int q = c * 4 + t;
            const float4 f = cur[t];
            const float* w1r = w1 + q * 4 * HIDN;
#pragma unroll
            for (int j = 0; j < HIDN; ++j) {
                hid[j] += f.x * w1r[j];
                hid[j] += f.y * w1r[HIDN + j];
                hid[j] += f.z * w1r[2 * HIDN + j];
                hid[j] += f.w * w1r[3 * HIDN + j];
            }
        }
#pragma unroll
        for (int t = 0; t < 4; ++t) cur[t] = nxt[t];
    }
    s0 = b2[0]; s1 = b2[1]; s2 = b2[2];
#pragma unroll
    for (int j = 0; j < HIDN; ++j) {
        float v = hid[j];
        v = v * __builtin_amdgcn_rcpf(1.0f + __expf(-v));   // silu
        s0 += v * w2[j * NH + 0];
        s1 += v * w2[j * NH + 1];
        s2 += v * w2[j * NH + 2];
    }
}

__device__ __forceinline__ float wave_max(float v) {
#pragma unroll
    for (int m = 32; m >= 1; m >>= 1) v = fmaxf(v, __shfl_xor(v, m, 64));
    return v;
}
__device__ __forceinline__ float wave_sum(float v) {
#pragma unroll
    for (int m = 32; m >= 1; m >>= 1) v += __shfl_xor(v, m, 64);
    return v;
}

// ---------------------------------------------------------------------------
// Rare path (seg > 64, P ~ 1e-4): 3-sweep with score recomputation.
// LDS-free, barrier-free; per-64-atom chunk weights broadcast via readlane.
// ---------------------------------------------------------------------------
__device__ __attribute__((noinline)) void big_segment_path(
    const float* __restrict__ feas, const float* __restrict__ w1,
    const float* __restrict__ b1, const float* __restrict__ w2,
    const float* __restrict__ b2, int lo, int hi, int lane,
    float* __restrict__ outg) {
    float m0 = -INFINITY, m1 = -INFINITY, m2 = -INFINITY;
    for (int base = lo; base < hi; base += 64) {
        int a = base + lane; if (a > hi - 1) a = hi - 1;
        float s0, s1, s2;
        mlp_scores(feas + (size_t)a * DD, w1, b1, w2, b2, s0, s1, s2);
        if (base + lane < hi) {
            m0 = fmaxf(m0, s0); m1 = fmaxf(m1, s1); m2 = fmaxf(m2, s2);
        }
    }
    m0 = wave_max(m0); m1 = wave_max(m1); m2 = wave_max(m2);
    float d0 = 0.f, d1 = 0.f, d2 = 0.f;
    for (int base = lo; base < hi; base += 64) {
        int a = base + lane; if (a > hi - 1) a = hi - 1;
        float s0, s1, s2;
        mlp_scores(feas + (size_t)a * DD, w1, b1, w2, b2, s0, s1, s2);
        bool act = (base + lane) < hi;
        d0 += act ? __expf(s0 - m0) : 0.f;
        d1 += act ? __expf(s1 - m1) : 0.f;
        d2 += act ? __expf(s2 - m2) : 0.f;
    }
    d0 = wave_sum(d0); d1 = wave_sum(d1); d2 = wave_sum(d2);
    const float rd0 = __builtin_amdgcn_rcpf(d0);
    const float rd1 = __builtin_amdgcn_rcpf(d1);
    const float rd2 = __builtin_amdgcn_rcpf(d2);
    float a0 = 0.f, a1 = 0.f, a2 = 0.f;
    for (int base = lo; base < hi; base += 64) {
        int a = base + lane; if (a > hi - 1) a = hi - 1;
        float s0, s1, s2;
        mlp_scores(feas + (size_t)a * DD, w1, b1, w2, b2, s0, s1, s2);
        bool act = (base + lane) < hi;
        float e0 = act ? __expf(s0 - m0) * rd0 : 0.f;
        float e1 = act ? __expf(s1 - m1) * rd1 : 0.f;
        float e2 = act ? __expf(s2 - m2) * rd2 : 0.f;
        int cnt = min(64, hi - base);
        const float* fb = feas + (size_t)base * DD + lane;
        for (int i = 0; i < cnt; ++i) {
            float f = fb[(size_t)i * DD];
            a0 += f * lane_bcast(e0, i);
            a1 += f * lane_bcast(e1, i);
            a2 += f * lane_bcast(e2, i);
        }
    }
    outg[lane * 3 + 0] = a0;
    outg[lane * 3 + 1] = a1;
    outg[lane * 3 + 2] = a2;
}

// ---------------------------------------------------------------------------
// Kernel 2: one wave per segment, WPB waves per block. ZERO LDS, zero
// barriers. seg<=64 fast path: lane i owns atom lo+i; softmax via shfl
// reductions; pooling weights broadcast via readlane; phase-3 feature
// re-reads unrolled x8 (8 loads in flight; lines are L1/L2/L3-warm).
// ---------------------------------------------------------------------------
__global__ void __launch_bounds__(WPB * 64) seg_attn_pool_k(
    const float* __restrict__ feas, const float* __restrict__ w1,
    const float* __restrict__ b1, const float* __restrict__ w2,
    const float* __restrict__ b2, const int* __restrict__ seg_start,
    float* __restrict__ out, int G) {
    const int g = blockIdx.x * WPB + (threadIdx.x >> 6);
    const int lane = threadIdx.x & 63;
    if (g >= G) return;
    const int lo = seg_start[g];
    const int hi = seg_start[g + 1];
    const int seg = hi - lo;
    float* outg = out + (size_t)g * (DD * NH);

    if (seg <= 0) {   // empty segment: reference segment_sum gives zeros
        outg[lane] = 0.f; outg[lane + 64] = 0.f; outg[lane + 128] = 0.f;
        return;
    }
    if (seg > 64) {
        big_segment_path(feas, w1, b1, w2, b2, lo, hi, lane, outg);
        return;
    }

    // ---- Phase 1: all lanes run the MLP unconditionally (clamped address),
    // inactive lanes get score = -INF so exp() contributes exactly 0.
    const int myatom = lo + min(lane, seg - 1);
    float s0, s1, s2;
    mlp_scores(feas + (size_t)myatom * DD, w1, b1, w2, b2, s0, s1, s2);
    if (lane >= seg) { s0 = -INFINITY; s1 = -INFINITY; s2 = -INFINITY; }

    // ---- Phase 2: segment softmax, register-only
    const float m0 = wave_max(s0), m1 = wave_max(s1), m2 = wave_max(s2);
    float e0 = __expf(s0 - m0);   // -INF -> 0 for inactive lanes
    float e1 = __expf(s1 - m1);
    float e2 = __expf(s2 - m2);
    const float rd0 = __builtin_amdgcn_rcpf(wave_sum(e0));
    const float rd1 = __builtin_amdgcn_rcpf(wave_sum(e1));
    const float rd2 = __builtin_amdgcn_rcpf(wave_sum(e2));
    e0 *= rd0; e1 *= rd1; e2 *= rd2;   // lane i holds attn[lo+i, :]

    // ---- Phase 3: weighted pooling, lane = feature dim d, unroll 8
    float a0 = 0.f, a1 = 0.f, a2 = 0.f;
    const float* fbase = feas + (size_t)lo * DD + lane;
    int i = 0;
    for (; i + 8 <= seg; i += 8) {
        float f[8];
#pragma unroll
        for (int u = 0; u < 8; ++u) f[u] = fbase[(size_t)(i + u) * DD];
#pragma unroll
        for (int u = 0; u < 8; ++u) {
            a0 += f[u] * lane_bcast(e0, i + u);
            a1 += f[u] * lane_bcast(e1, i + u);
            a2 += f[u] * lane_bcast(e2, i + u);
        }
    }
    for (; i < seg; ++i) {
        float f = fbase[(size_t)i * DD];
        a0 += f * lane_bcast(e0, i);
        a1 += f * lane_bcast(e1, i);
        a2 += f * lane_bcast(e2, i);
    }

    // out[g, d, h], head fastest: 12B/lane, contiguous 768B per wave
    outg[lane * 3 + 0] = a0;
    outg[lane * 3 + 1] = a1;
    outg[lane * 3 + 2] = a2;
}

extern "C" void kernel_launch(void* const* d_in, const int* in_sizes, int n_in,
                              void* d_out, int out_size, void* d_ws, size_t ws_size,
                              hipStream_t stream) {
    const float* feas  = (const float*)d_in[0];
    const float* w1    = (const float*)d_in[1];
    const float* b1    = (const float*)d_in[2];
    const float* w2    = (const float*)d_in[3];
    const float* b2    = (const float*)d_in[4];
    const int*   owner = (const int*)d_in[5];
    const int N = in_sizes[5];
    const int G = out_size / (DD * NH);

    int* seg_start = (int*)d_ws;                // (G+1) ints ~ 200 KB
    float* out = (float*)d_out;

    seg_offsets_k<<<(N + 255) / 256, 256, 0, stream>>>(owner, N, G, seg_start);
    seg_attn_pool_k<<<(G + WPB - 1) / WPB, WPB * 64, 0, stream>>>(
        feas, w1, b1, w2, b2, seg_start, out, G);
}